// Round 3
// baseline (211.439 us; speedup 1.0000x reference)
//
#include <hip/hip_runtime.h>

#define HW      147456           // 384*384
#define NC      5
#define NT      40               // 4*10
#define GX      144              // HW / (256 threads * 4 px) = 147456/1024
#define NBLK    (GX * NT)        // 5760 blocks
#define SMOOTH  1e-5f

// ---------------------------------------------------------------------------
// Pass 1: 2D grid (GX, NT). One float4 pixel-group per thread — no division,
// no grid-stride loop; 6 independent 16B loads issue back-to-back.
// Per-block 15 partials written non-atomically to part[blk*16 + j].
// j: 0..4 = sum_x[c], 5..9 = inter[c], 10..14 = count[c], 15 = pad(0)
// ---------------------------------------------------------------------------
__global__ __launch_bounds__(256) void dice_main(const float* __restrict__ inp,
                                                 const float* __restrict__ tgt,
                                                 float* __restrict__ part) {
    const int nt = blockIdx.y;
    const int hw = (blockIdx.x * 256 + threadIdx.x) << 2;

    const float4 t4 = *reinterpret_cast<const float4*>(tgt + (size_t)nt * HW + hw);

    const float* base = inp + (size_t)nt * (NC * HW) + hw;
    const float4 x0 = *reinterpret_cast<const float4*>(base);
    const float4 x1 = *reinterpret_cast<const float4*>(base + HW);
    const float4 x2 = *reinterpret_cast<const float4*>(base + 2 * HW);
    const float4 x3 = *reinterpret_cast<const float4*>(base + 3 * HW);
    const float4 x4 = *reinterpret_cast<const float4*>(base + 4 * HW);

    const int c0 = (t4.x >= 0.25f) + (t4.x >= 0.375f) + (t4.x >= 0.5f) + (t4.x >= 0.625f);
    const int c1 = (t4.y >= 0.25f) + (t4.y >= 0.375f) + (t4.y >= 0.5f) + (t4.y >= 0.625f);
    const int c2 = (t4.z >= 0.25f) + (t4.z >= 0.375f) + (t4.z >= 0.5f) + (t4.z >= 0.625f);
    const int c3 = (t4.w >= 0.25f) + (t4.w >= 0.375f) + (t4.w >= 0.5f) + (t4.w >= 0.625f);

    const float4 xs[NC] = {x0, x1, x2, x3, x4};
    float v[15];
    #pragma unroll
    for (int c = 0; c < NC; ++c) {
        const float4 x = xs[c];
        v[c] = (x.x + x.y) + (x.z + x.w);               // sum_x
        float iv = 0.f;
        if (c0 == c) iv += x.x;
        if (c1 == c) iv += x.y;
        if (c2 == c) iv += x.z;
        if (c3 == c) iv += x.w;
        v[5 + c]  = iv;                                  // inter
        v[10 + c] = (float)((c0 == c) + (c1 == c) + (c2 == c) + (c3 == c));  // count
    }

    // wave-64 butterfly reduce
    #pragma unroll
    for (int j = 0; j < 15; ++j) {
        #pragma unroll
        for (int off = 32; off > 0; off >>= 1)
            v[j] += __shfl_down(v[j], off, 64);
    }

    __shared__ float sm[4][15];
    const int lane = threadIdx.x & 63;
    const int wv   = threadIdx.x >> 6;
    if (lane == 0) {
        #pragma unroll
        for (int j = 0; j < 15; ++j) sm[wv][j] = v[j];
    }
    __syncthreads();
    if (threadIdx.x < 16) {
        float s = 0.f;
        if (threadIdx.x < 15)
            s = sm[0][threadIdx.x] + sm[1][threadIdx.x] +
                sm[2][threadIdx.x] + sm[3][threadIdx.x];
        part[(blockIdx.y * GX + blockIdx.x) * 16 + threadIdx.x] = s;
    }
}

// ---------------------------------------------------------------------------
// Pass 2: one block reduces NBLK*16 partials and computes the weighted dice.
// ---------------------------------------------------------------------------
__global__ __launch_bounds__(256) void dice_reduce(const float* __restrict__ part,
                                                   const float* __restrict__ w,
                                                   float* __restrict__ out) {
    const int j  = threadIdx.x & 15;   // accumulator index
    const int rg = threadIdx.x >> 4;   // row group 0..15
    float s0 = 0.f, s1 = 0.f, s2 = 0.f, s3 = 0.f;
    for (int r = rg; r < NBLK; r += 64) {              // NBLK % 64 == 0
        s0 += part[(r)      * 16 + j];
        s1 += part[(r + 16) * 16 + j];
        s2 += part[(r + 32) * 16 + j];
        s3 += part[(r + 48) * 16 + j];
    }
    const float s = (s0 + s1) + (s2 + s3);

    __shared__ float sm[16][17];
    __shared__ float tot[16];
    sm[rg][j] = s;
    __syncthreads();
    if (threadIdx.x < 16) {
        float t = 0.f;
        #pragma unroll
        for (int k = 0; k < 16; ++k) t += sm[k][threadIdx.x];
        tot[threadIdx.x] = t;
    }
    __syncthreads();
    if (threadIdx.x == 0) {
        float loss = 0.f;
        #pragma unroll
        for (int c = 0; c < NC; ++c) {
            const float inter = tot[5 + c];
            const float denom = tot[c] + tot[10 + c];
            loss += w[c] * (1.f - (2.f * inter + SMOOTH) / (denom + SMOOTH));
        }
        out[0] = loss;
    }
}

extern "C" void kernel_launch(void* const* d_in, const int* in_sizes, int n_in,
                              void* d_out, int out_size, void* d_ws, size_t ws_size,
                              hipStream_t stream) {
    const float* inp = (const float*)d_in[0];
    const float* tgt = (const float*)d_in[1];
    const float* wgt = (const float*)d_in[2];
    float* out = (float*)d_out;
    float* ws  = (float*)d_ws;

    dim3 grid(GX, NT);
    dice_main<<<grid, 256, 0, stream>>>(inp, tgt, ws);
    dice_reduce<<<1, 256, 0, stream>>>(ws, wgt, out);
}

// Round 5
// 199.399 us; speedup vs baseline: 1.0604x; 1.0604x over previous
//
#include <hip/hip_runtime.h>

#define HW      147456           // 384*384
#define NC      5
#define NT      40               // 4*10
#define GX      36               // HW / (256 threads * 4 groups * 4 px)
#define NBLK    (GX * NT)        // 1440 blocks
#define SMOOTH  1e-5f

// ext_vector_type so __builtin_nontemporal_load accepts the pointer
typedef float vfloat4 __attribute__((ext_vector_type(4)));

// ---------------------------------------------------------------------------
// Pass 1: 2D grid (GX=36, NT=40), 256 threads, 4 float4-groups per thread.
// Groups for thread t: hw0 + t*4 + {0,1024,2048,3072} floats (coalesced waves).
// 24 nontemporal 16B loads issued back-to-back, then branch-free accumulate,
// one 15-value wave/block reduce, non-atomic partial write.
// j: 0..4 = sum_x[c], 5..9 = inter[c], 10..14 = count[c], 15 = pad
// ---------------------------------------------------------------------------
__global__ __launch_bounds__(256) void dice_main(const float* __restrict__ inp,
                                                 const float* __restrict__ tgt,
                                                 float* __restrict__ part) {
    const int nt  = blockIdx.y;
    const int hw0 = blockIdx.x * 4096 + (threadIdx.x << 2);  // 256 thr * 4 groups * 4 px

    const float* tb = tgt + (size_t)nt * HW + hw0;
    const float* xb = inp + (size_t)nt * (NC * HW) + hw0;

    vfloat4 t4[4];
    vfloat4 x4[4][NC];
    #pragma unroll
    for (int g = 0; g < 4; ++g)
        t4[g] = __builtin_nontemporal_load(reinterpret_cast<const vfloat4*>(tb + g * 1024));
    #pragma unroll
    for (int g = 0; g < 4; ++g)
        #pragma unroll
        for (int c = 0; c < NC; ++c)
            x4[g][c] = __builtin_nontemporal_load(
                reinterpret_cast<const vfloat4*>(xb + (size_t)c * HW + g * 1024));

    float v[15];
    #pragma unroll
    for (int j = 0; j < 15; ++j) v[j] = 0.f;

    #pragma unroll
    for (int g = 0; g < 4; ++g) {
        const vfloat4 t = t4[g];
        const int c0 = (t.x >= 0.25f) + (t.x >= 0.375f) + (t.x >= 0.5f) + (t.x >= 0.625f);
        const int c1 = (t.y >= 0.25f) + (t.y >= 0.375f) + (t.y >= 0.5f) + (t.y >= 0.625f);
        const int c2 = (t.z >= 0.25f) + (t.z >= 0.375f) + (t.z >= 0.5f) + (t.z >= 0.625f);
        const int c3 = (t.w >= 0.25f) + (t.w >= 0.375f) + (t.w >= 0.5f) + (t.w >= 0.625f);
        #pragma unroll
        for (int c = 0; c < NC; ++c) {
            const vfloat4 x = x4[g][c];
            v[c] += (x.x + x.y) + (x.z + x.w);          // sum_x
            float iv = 0.f;
            if (c0 == c) iv += x.x;
            if (c1 == c) iv += x.y;
            if (c2 == c) iv += x.z;
            if (c3 == c) iv += x.w;
            v[5 + c]  += iv;                             // inter
            v[10 + c] += (float)((c0 == c) + (c1 == c) + (c2 == c) + (c3 == c));
        }
    }

    // wave-64 butterfly reduce (amortized over 4 groups/thread now)
    #pragma unroll
    for (int j = 0; j < 15; ++j) {
        #pragma unroll
        for (int off = 32; off > 0; off >>= 1)
            v[j] += __shfl_down(v[j], off, 64);
    }

    __shared__ float sm[4][15];
    const int lane = threadIdx.x & 63;
    const int wv   = threadIdx.x >> 6;
    if (lane == 0) {
        #pragma unroll
        for (int j = 0; j < 15; ++j) sm[wv][j] = v[j];
    }
    __syncthreads();
    if (threadIdx.x < 16) {
        float s = 0.f;
        if (threadIdx.x < 15)
            s = sm[0][threadIdx.x] + sm[1][threadIdx.x] +
                sm[2][threadIdx.x] + sm[3][threadIdx.x];
        part[(blockIdx.y * GX + blockIdx.x) * 16 + threadIdx.x] = s;
    }
}

// ---------------------------------------------------------------------------
// Pass 2: one block reduces NBLK*16 partials and computes the weighted dice.
// ---------------------------------------------------------------------------
__global__ __launch_bounds__(256) void dice_reduce(const float* __restrict__ part,
                                                   const float* __restrict__ w,
                                                   float* __restrict__ out) {
    const int j  = threadIdx.x & 15;   // accumulator index
    const int rg = threadIdx.x >> 4;   // row group 0..15
    float s = 0.f;
    for (int r = rg; r < NBLK; r += 16)   // 90 iters, coalesced
        s += part[r * 16 + j];

    __shared__ float sm[16][17];
    __shared__ float tot[16];
    sm[rg][j] = s;
    __syncthreads();
    if (threadIdx.x < 16) {
        float t = 0.f;
        #pragma unroll
        for (int k = 0; k < 16; ++k) t += sm[k][threadIdx.x];
        tot[threadIdx.x] = t;
    }
    __syncthreads();
    if (threadIdx.x == 0) {
        float loss = 0.f;
        #pragma unroll
        for (int c = 0; c < NC; ++c) {
            const float inter = tot[5 + c];
            const float denom = tot[c] + tot[10 + c];
            loss += w[c] * (1.f - (2.f * inter + SMOOTH) / (denom + SMOOTH));
        }
        out[0] = loss;
    }
}

extern "C" void kernel_launch(void* const* d_in, const int* in_sizes, int n_in,
                              void* d_out, int out_size, void* d_ws, size_t ws_size,
                              hipStream_t stream) {
    const float* inp = (const float*)d_in[0];
    const float* tgt = (const float*)d_in[1];
    const float* wgt = (const float*)d_in[2];
    float* out = (float*)d_out;
    float* ws  = (float*)d_ws;

    dim3 grid(GX, NT);
    dice_main<<<grid, 256, 0, stream>>>(inp, tgt, ws);
    dice_reduce<<<1, 256, 0, stream>>>(ws, wgt, out);
}